// Round 16
// baseline (29.384 us; speedup 1.0000x reference)
//
#include <hip/hip_runtime.h>

// Problem constants (fixed by setup_inputs)
#define K   19
#define C   256
#define HF  64
#define WF  128
#define HW  (HF * WF)
#define BB  4
#define HL  512
#define WL  1024

// f32 near-tie threshold: f32 distance error bound < ~1e-3; pixels whose
// top-2 f32 gap < TAU get an exact f64 cooperative resolve (same wave).
#define TAU 0.015f

// Block = 256 thr = 4 waves, tile = 64 px (lane = pixel). Wave wv owns
// channels [wv*64, wv*64+64). KEY CHANGE vs R15: the 64 feature loads are
// issued as VOLATILE INLINE-ASM global_load_dword -- in order, back-to-back,
// all 64 in the vmcnt queue (4x R15's chunk depth of 8), and the outputs
// cannot be rematerialized or sunk (R4-R15: compiler-issued loads were
// re-batched to depth ~8, effective HBM ~2 TB/s = 31% of achievable).
// One s_waitcnt vmcnt(0) + sched_barrier(0) fence (rule: FMAs must not be
// scheduled into the async window), then a pure-register FMA loop.
__global__ __launch_bounds__(256, 4) void centroid_mask_kernel(
    const float* __restrict__ feat0,   // feature_s2t
    const float* __restrict__ feat1,   // feature_target
    const float* __restrict__ cent0,   // centroids for map 0 (centroid_target)
    const float* __restrict__ cent1,   // centroids for map 1 (centroid_s2t)
    int* __restrict__ out)             // [2][BB][HL][WL] int32
{
    __shared__ float  part[4 * K * 64];  // [wv][k][px], px stride 1: conflict-free
    __shared__ double c2p[K][8];         // exact ||c||^2 partials
    __shared__ double sc2d[K];           // exact ||c||^2 (f64)
    __shared__ float  sc2f[K];           // rounded-exact ||c||^2 (f32)

    const int map = blockIdx.y;
    const float* __restrict__ feat = (map == 0) ? feat0 : feat1;
    const float* __restrict__ cent = (map == 0) ? cent0 : cent1;

    const int tid  = threadIdx.x;
    const int lane = tid & 63;
    const int wv   = __builtin_amdgcn_readfirstlane(tid >> 6);   // 0..3, uniform

    // exact ||c_k||^2 partials (f64), 152 threads, overlaps with main
    if (tid < K * 8) {
        const int k = tid >> 3, sl = tid & 7;
        const float* cp = cent + k * C + sl * 32;
        double s = 0.0;
        #pragma unroll
        for (int j = 0; j < 32; ++j) { double v = (double)cp[j]; s = fma(v, v, s); }
        c2p[k][sl] = s;
    }

    const int p  = blockIdx.x * 64 + lane;     // pixel in [0, 32768)
    const int hw = p & (HW - 1);
    const int b  = p >> 13;
    const int cb = wv * 64;

    const float* __restrict__ fp = feat + (size_t)b * C * HW + (size_t)cb * HW + hw;
    const float* __restrict__ cw = cent + cb;            // + k*C + ch (uniform)

    // ---- issue ALL 64 feature loads: volatile asm, 64-deep vmcnt queue ----
    float f[64];
    #pragma unroll
    for (int i = 0; i < 64; ++i) {
        const float* a = fp + (size_t)i * HW;
        asm volatile("global_load_dword %0, %1, off" : "=v"(f[i]) : "v"(a));
    }
    asm volatile("s_waitcnt vmcnt(0)" ::: "memory");
    __builtin_amdgcn_sched_barrier(0);   // fence: nothing moves into the window

    float acc[K];
    #pragma unroll
    for (int k = 0; k < K; ++k) acc[k] = 0.f;

    // pure-register FMA loop; centroid operand wave-uniform (s_load/SGPR)
    #pragma unroll
    for (int ch = 0; ch < 8; ++ch) {
        #pragma unroll
        for (int k = 0; k < K; ++k) {
            const float* __restrict__ ck = cw + (size_t)k * C + ch * 8;
            float a = acc[k];
            a = fmaf(f[ch*8+0], ck[0], a); a = fmaf(f[ch*8+1], ck[1], a);
            a = fmaf(f[ch*8+2], ck[2], a); a = fmaf(f[ch*8+3], ck[3], a);
            a = fmaf(f[ch*8+4], ck[4], a); a = fmaf(f[ch*8+5], ck[5], a);
            a = fmaf(f[ch*8+6], ck[6], a); a = fmaf(f[ch*8+7], ck[7], a);
            acc[k] = a;
        }
    }

    // write this wave's full-64-channel partial dots (lane-contiguous)
    float* __restrict__ pw = &part[(wv * K) * 64 + lane];
    #pragma unroll
    for (int k = 0; k < K; ++k) pw[k * 64] = acc[k];
    __syncthreads();

    if (tid < K) {
        double s = 0.0;
        #pragma unroll
        for (int j = 0; j < 8; ++j) s += c2p[tid][j];
        sc2d[tid] = s;
        sc2f[tid] = (float)s;
    }
    __syncthreads();

    // ---- epilogue: wave 0, lane = pixel (R15 verbatim) ----
    if (tid < 64) {
        const int pix = tid;
        float d[K];
        #pragma unroll
        for (int k = 0; k < K; ++k) {
            const float s = (part[(0 * K + k) * 64 + pix] + part[(1 * K + k) * 64 + pix])
                          + (part[(2 * K + k) * 64 + pix] + part[(3 * K + k) * 64 + pix]);
            d[k] = sc2f[k] - 2.0f * s;
        }
        int best = 0; float m1 = d[0];
        #pragma unroll
        for (int k = 1; k < K; ++k) if (d[k] < m1) { m1 = d[k]; best = k; }

        // near-tie candidates within TAU of the f32 min (always includes best)
        unsigned cmask = 0u;
        #pragma unroll
        for (int k = 0; k < K; ++k) if (d[k] - m1 < TAU) cmask |= (1u << k);

        // cooperative exact-f64 resolve of flagged pixels (proven, R8)
        const bool need = (cmask & (cmask - 1)) != 0u;
        unsigned long long ball = __ballot(need);
        while (ball) {
            const int px = (int)__builtin_ctzll(ball);   // lowest flagged lane
            ball &= ball - 1;
            const unsigned pm  = __shfl(cmask, px, 64);
            const int      phw = __shfl(hw,    px, 64);
            const int      pb  = __shfl(b,     px, 64);
            const float* __restrict__ fcol = feat + (size_t)pb * C * HW + phw;

            const int c0 = tid << 2;                     // channels 4l..4l+3
            double pf[4];
            #pragma unroll
            for (int j = 0; j < 4; ++j)
                pf[j] = (double)fcol[(size_t)(c0 + j) * HW];

            double bd = 1e300; int bi = 0;
            unsigned mm = pm;
            while (mm) {                      // ascending k, strict < tie-break
                const int k = (int)__builtin_ctz(mm);
                mm &= mm - 1;
                const float* __restrict__ ck = cent + (size_t)k * C + c0;
                double s = 0.0;
                #pragma unroll
                for (int j = 0; j < 4; ++j)
                    s = fma(pf[j], (double)ck[j], s);
                #pragma unroll
                for (int off = 1; off < 64; off <<= 1)
                    s += __shfl_xor(s, off, 64);
                const double dk = sc2d[k] - 2.0 * s;
                if (dk < bd) { bd = dk; bi = k; }
            }
            if (tid == px) best = bi;         // all lanes agree on bi
        }

        // write the 8x8 nearest-upsampled block
        const int w = hw & (WF - 1);
        const int h = hw >> 7;
        int4 v = make_int4(best, best, best, best);
        int* __restrict__ ob = out + (size_t)map * (BB * HL * WL)
                                   + (size_t)b * (HL * WL)
                                   + (size_t)(h * 8) * WL + (size_t)(w * 8);
        #pragma unroll
        for (int r = 0; r < 8; ++r) {
            *(int4*)(ob + (size_t)r * WL)     = v;
            *(int4*)(ob + (size_t)r * WL + 4) = v;
        }
    }
}

extern "C" void kernel_launch(void* const* d_in, const int* in_sizes, int n_in,
                              void* d_out, int out_size, void* d_ws, size_t ws_size,
                              hipStream_t stream) {
    const float* feature_s2t     = (const float*)d_in[0];
    const float* feature_target  = (const float*)d_in[1];
    // d_in[2], d_in[3]: labels — only shapes matter, unused
    const float* centroid_s2t    = (const float*)d_in[4];
    const float* centroid_target = (const float*)d_in[5];
    int* out = (int*)d_out;

    dim3 grid(32768 / 64, 2);   // (512, 2) -> 1024 blocks, all resident (4/CU)
    dim3 block(256);
    hipLaunchKernelGGL(centroid_mask_kernel, grid, block, 0, stream,
                       feature_s2t, feature_target,
                       centroid_target, centroid_s2t, out);
}

// Round 17
// 24.447 us; speedup vs baseline: 1.2020x; 1.2020x over previous
//
#include <hip/hip_runtime.h>

// Problem constants (fixed by setup_inputs)
#define K   19
#define C   256
#define HF  64
#define WF  128
#define HW  (HF * WF)
#define BB  4
#define HL  512
#define WL  1024

// f32 near-tie threshold: f32 distance error bound < ~1e-3; pixels whose
// top-2 f32 gap < TAU get an exact f64 cooperative resolve (same wave).
#define TAU 0.015f

// Block = 512 thr = 8 waves, tile = 64 px (lane = pixel). Wave wv owns
// channels [wv*32, wv*32+32): 4 chunks x (8 batched coalesced loads + 152
// FMAs from REGISTERS with SGPR centroid operand). KEY vs R15: 8 waves/SIMD
// (launch_bounds (512,8)) -- chunk-outer's live set is only f8[8]+acc[19]
// ~45 VGPR, so the 64-VGPR cap does NOT trigger R4's k-outer remat disease,
// and the per-chunk load/s_load stalls are now 8-way covered instead of
// 4-way (R15/R16 ran 4 waves/SIMD; every micro-variant of the memory path
// at that occupancy landed 25-29us). Per-wave s_load footprint 2.4 KB
// (fits scalar L1). Epilogue + cooperative-f64 fallback: R8/R15 verbatim.
__global__ __launch_bounds__(512, 8) void centroid_mask_kernel(
    const float* __restrict__ feat0,   // feature_s2t
    const float* __restrict__ feat1,   // feature_target
    const float* __restrict__ cent0,   // centroids for map 0 (centroid_target)
    const float* __restrict__ cent1,   // centroids for map 1 (centroid_s2t)
    int* __restrict__ out)             // [2][BB][HL][WL] int32
{
    __shared__ float  part[8 * K * 64];  // [wv][k][px], px stride 1: conflict-free
    __shared__ double c2p[K][8];         // exact ||c||^2 partials
    __shared__ double sc2d[K];           // exact ||c||^2 (f64)
    __shared__ float  sc2f[K];           // rounded-exact ||c||^2 (f32)

    const int map = blockIdx.y;
    const float* __restrict__ feat = (map == 0) ? feat0 : feat1;
    const float* __restrict__ cent = (map == 0) ? cent0 : cent1;

    const int tid  = threadIdx.x;
    const int lane = tid & 63;
    const int wv   = __builtin_amdgcn_readfirstlane(tid >> 6);   // 0..7, uniform

    // exact ||c_k||^2 partials (f64), 152 threads, overlaps with main
    if (tid < K * 8) {
        const int k = tid >> 3, sl = tid & 7;
        const float* cp = cent + k * C + sl * 32;
        double s = 0.0;
        #pragma unroll
        for (int j = 0; j < 32; ++j) { double v = (double)cp[j]; s = fma(v, v, s); }
        c2p[k][sl] = s;
    }

    const int p  = blockIdx.x * 64 + lane;     // pixel in [0, 32768)
    const int hw = p & (HW - 1);
    const int b  = p >> 13;
    const int cb = wv * 32;

    const float* __restrict__ fp = feat + (size_t)b * C * HW + (size_t)cb * HW + hw;
    const float* __restrict__ cw = cent + cb;            // + k*C + ch (uniform)

    float acc[K];
    #pragma unroll
    for (int k = 0; k < K; ++k) acc[k] = 0.f;

    // 4 chunks of 8 channels: load f8 once (8 independent coalesced loads,
    // batch-issued), then 19x8 FMAs from registers, SGPR centroid operand.
    #pragma unroll
    for (int ch = 0; ch < 4; ++ch) {
        float f8[8];
        #pragma unroll
        for (int i = 0; i < 8; ++i)
            f8[i] = fp[(size_t)(ch * 8 + i) * HW];
        #pragma unroll
        for (int k = 0; k < K; ++k) {
            const float* __restrict__ ck = cw + (size_t)k * C + ch * 8;
            float a = acc[k];
            a = fmaf(f8[0], ck[0], a); a = fmaf(f8[1], ck[1], a);
            a = fmaf(f8[2], ck[2], a); a = fmaf(f8[3], ck[3], a);
            a = fmaf(f8[4], ck[4], a); a = fmaf(f8[5], ck[5], a);
            a = fmaf(f8[6], ck[6], a); a = fmaf(f8[7], ck[7], a);
            acc[k] = a;
        }
    }

    // write this wave's 32-channel partial dots (lane-contiguous)
    float* __restrict__ pw = &part[(wv * K) * 64 + lane];
    #pragma unroll
    for (int k = 0; k < K; ++k) pw[k * 64] = acc[k];
    __syncthreads();

    if (tid < K) {
        double s = 0.0;
        #pragma unroll
        for (int j = 0; j < 8; ++j) s += c2p[tid][j];
        sc2d[tid] = s;
        sc2f[tid] = (float)s;
    }
    __syncthreads();

    // ---- epilogue: wave 0, lane = pixel (R8/R15 verbatim, 8-way part sum) ----
    if (tid < 64) {
        const int pix = tid;
        float d[K];
        #pragma unroll
        for (int k = 0; k < K; ++k) {
            float s = 0.f;
            #pragma unroll
            for (int w8 = 0; w8 < 8; ++w8)
                s += part[(w8 * K + k) * 64 + pix];
            d[k] = sc2f[k] - 2.0f * s;
        }
        int best = 0; float m1 = d[0];
        #pragma unroll
        for (int k = 1; k < K; ++k) if (d[k] < m1) { m1 = d[k]; best = k; }

        // near-tie candidates within TAU of the f32 min (always includes best)
        unsigned cmask = 0u;
        #pragma unroll
        for (int k = 0; k < K; ++k) if (d[k] - m1 < TAU) cmask |= (1u << k);

        // cooperative exact-f64 resolve of flagged pixels (proven, R8)
        const bool need = (cmask & (cmask - 1)) != 0u;
        unsigned long long ball = __ballot(need);
        while (ball) {
            const int px = (int)__builtin_ctzll(ball);   // lowest flagged lane
            ball &= ball - 1;
            const unsigned pm  = __shfl(cmask, px, 64);
            const int      phw = __shfl(hw,    px, 64);
            const int      pb  = __shfl(b,     px, 64);
            const float* __restrict__ fcol = feat + (size_t)pb * C * HW + phw;

            const int c0 = tid << 2;                     // channels 4l..4l+3
            double pf[4];
            #pragma unroll
            for (int j = 0; j < 4; ++j)
                pf[j] = (double)fcol[(size_t)(c0 + j) * HW];

            double bd = 1e300; int bi = 0;
            unsigned mm = pm;
            while (mm) {                      // ascending k, strict < tie-break
                const int k = (int)__builtin_ctz(mm);
                mm &= mm - 1;
                const float* __restrict__ ck = cent + (size_t)k * C + c0;
                double s = 0.0;
                #pragma unroll
                for (int j = 0; j < 4; ++j)
                    s = fma(pf[j], (double)ck[j], s);
                #pragma unroll
                for (int off = 1; off < 64; off <<= 1)
                    s += __shfl_xor(s, off, 64);
                const double dk = sc2d[k] - 2.0 * s;
                if (dk < bd) { bd = dk; bi = k; }
            }
            if (tid == px) best = bi;         // all lanes agree on bi
        }

        // write the 8x8 nearest-upsampled block
        const int w = hw & (WF - 1);
        const int h = hw >> 7;
        int4 v = make_int4(best, best, best, best);
        int* __restrict__ ob = out + (size_t)map * (BB * HL * WL)
                                   + (size_t)b * (HL * WL)
                                   + (size_t)(h * 8) * WL + (size_t)(w * 8);
        #pragma unroll
        for (int r = 0; r < 8; ++r) {
            *(int4*)(ob + (size_t)r * WL)     = v;
            *(int4*)(ob + (size_t)r * WL + 4) = v;
        }
    }
}

extern "C" void kernel_launch(void* const* d_in, const int* in_sizes, int n_in,
                              void* d_out, int out_size, void* d_ws, size_t ws_size,
                              hipStream_t stream) {
    const float* feature_s2t     = (const float*)d_in[0];
    const float* feature_target  = (const float*)d_in[1];
    // d_in[2], d_in[3]: labels — only shapes matter, unused
    const float* centroid_s2t    = (const float*)d_in[4];
    const float* centroid_target = (const float*)d_in[5];
    int* out = (int*)d_out;

    dim3 grid(32768 / 64, 2);   // (512, 2) -> 1024 blocks, 4/CU, 32 waves/CU
    dim3 block(512);
    hipLaunchKernelGGL(centroid_mask_kernel, grid, block, 0, stream,
                       feature_s2t, feature_target,
                       centroid_target, centroid_s2t, out);
}

// Round 19
// 22.723 us; speedup vs baseline: 1.2932x; 1.0759x over previous
//
#include <hip/hip_runtime.h>

// Problem constants (fixed by setup_inputs)
#define K   19
#define C   256
#define HF  64
#define WF  128
#define HW  (HF * WF)
#define BB  4
#define HL  512
#define WL  1024

// bf16-split-x3 distance error bound ~1e-3 worst-case; pixels whose top-2
// gap < TAU get the proven exact-f64 cooperative resolve.
#define TAU 0.03f

#define CPAD 264    // halfwords per centroid row: 528 B = 33 x 16 B (b128-aligned)
#define DPAD 66     // dwords per acc row

typedef __attribute__((ext_vector_type(8)))  short bf16x8;
typedef __attribute__((ext_vector_type(16))) float f32x16;

// MFMA rewrite (R18 + ONE FIX): R18's B-fragment index was missing the
// kh*128 K-half offset -- the kh=1 wave multiplied feature channels 128-255
// by centroid channels 0-127 (absmax=18). Fixed: bidx includes kh*128.
// C[px][k] = sum_c f[px][c]*cent[k][c] as GEMM (M=65536, N=19, K=256); f32
// emulated as bf16_hi+bf16_lo, dot via 3x mfma_f32_32x32x16_bf16 into one
// f32 accumulator. Block = 256 thr = 4 waves = 2 tiles x 2 K-halves.
__global__ __launch_bounds__(256, 4) void centroid_mask_kernel(
    const float* __restrict__ feat0,   // feature_s2t
    const float* __restrict__ feat1,   // feature_target
    const float* __restrict__ cent0,   // centroids for map 0 (centroid_target)
    const float* __restrict__ cent1,   // centroids for map 1 (centroid_s2t)
    int* __restrict__ out)             // [2][BB][HL][WL] int32
{
    __shared__ __align__(16) unsigned short chi[K * CPAD];  // centroid hi bf16
    __shared__ __align__(16) unsigned short clo[K * CPAD];  // centroid lo bf16
    __shared__ float  dbuf[2][2][16][DPAD];  // [tile][khalf][reg][32h+k]
    __shared__ double c2p[K][8];             // exact ||c||^2 partials
    __shared__ double sc2d[K];               // exact ||c||^2 (f64)
    __shared__ float  sc2f[K];               // rounded-exact ||c||^2 (f32)

    const int map = blockIdx.y;
    const float* __restrict__ feat = (map == 0) ? feat0 : feat1;
    const float* __restrict__ cent = (map == 0) ? cent0 : cent1;

    const int tid  = threadIdx.x;
    const int lane = tid & 63;
    const int wv   = __builtin_amdgcn_readfirstlane(tid >> 6);   // 0..3, uniform

    // ---- stage split centroids into LDS (coalesced) + exact ||c||^2 ----
    for (int i = tid; i < K * C; i += 256) {
        const int k = i >> 8, c = i & (C - 1);
        const unsigned u = __float_as_uint(cent[i]);
        const float r = __uint_as_float(u) - __uint_as_float(u & 0xffff0000u);
        chi[k * CPAD + c] = (unsigned short)(u >> 16);
        clo[k * CPAD + c] = (unsigned short)(__float_as_uint(r) >> 16);
    }
    if (tid < K * 8) {
        const int k = tid >> 3, sl = tid & 7;
        const float* cp = cent + k * C + sl * 32;
        double s = 0.0;
        #pragma unroll
        for (int j = 0; j < 32; ++j) { double v = (double)cp[j]; s = fma(v, v, s); }
        c2p[k][sl] = s;
    }
    __syncthreads();
    if (tid < K) {
        double s = 0.0;
        #pragma unroll
        for (int j = 0; j < 8; ++j) s += c2p[tid][j];
        sc2d[tid] = s;
        sc2f[tid] = (float)s;
    }

    // ---- main: wave = (tile, khalf); 32 px x 19 k, K-half = 128 ch ----
    const int tile = wv >> 1, kh = wv & 1;
    const int hl2  = (lane >> 5) & 1;              // k-subchunk select
    const int pp   = blockIdx.x * 64 + tile * 32 + (lane & 31);
    const int hw   = pp & (HW - 1);
    const int b    = pp >> 13;

    const float* __restrict__ fp = feat + (size_t)b * C * HW + hw;
    const int cb0  = kh * 128 + hl2 * 8;           // A channel base for this lane
    // B-frag LDS base: centroid row (lane&31, clamped), SAME channel range as A
    const int bidx = min(lane & 31, 18) * CPAD + kh * 128 + hl2 * 8;   // FIX: +kh*128

    f32x16 acc;
    #pragma unroll
    for (int r = 0; r < 16; ++r) acc[r] = 0.f;

    #pragma unroll
    for (int s = 0; s < 8; ++s) {                  // 8 K-steps of 16
        const int cb = cb0 + s * 16;
        float fv[8];
        #pragma unroll
        for (int j = 0; j < 8; ++j)
            fv[j] = fp[(size_t)(cb + j) * HW];     // coalesced over lanes 0-31

        union { unsigned u[4]; bf16x8 v; } ah, al, bh, bl;
        #pragma unroll
        for (int j = 0; j < 4; ++j) {
            const unsigned u0 = __float_as_uint(fv[2*j]);
            const unsigned u1 = __float_as_uint(fv[2*j+1]);
            ah.u[j] = (u0 >> 16) | (u1 & 0xffff0000u);           // hi (truncate)
            const float r0 = fv[2*j]   - __uint_as_float(u0 & 0xffff0000u);
            const float r1 = fv[2*j+1] - __uint_as_float(u1 & 0xffff0000u);
            al.u[j] = (__float_as_uint(r0) >> 16)
                    | (__float_as_uint(r1) & 0xffff0000u);       // lo (truncate)
        }
        bh.v = *(const bf16x8*)&chi[bidx + s * 16];
        bl.v = *(const bf16x8*)&clo[bidx + s * 16];

        acc = __builtin_amdgcn_mfma_f32_32x32x16_bf16(ah.v, bh.v, acc, 0, 0, 0);
        acc = __builtin_amdgcn_mfma_f32_32x32x16_bf16(ah.v, bl.v, acc, 0, 0, 0);
        acc = __builtin_amdgcn_mfma_f32_32x32x16_bf16(al.v, bh.v, acc, 0, 0, 0);
    }

    // dump acc: element (reg, lane) = D[px=(reg&3)+8(reg>>2)+4(lane>>5)][k=lane&31]
    {
        float* dst = &dbuf[tile][kh][0][hl2 * 32 + (lane & 31)];
        #pragma unroll
        for (int r = 0; r < 16; ++r) dst[r * DPAD] = acc[r];
    }
    __syncthreads();

    // ---- epilogue: wave 0, lane = pixel (both tiles); R8 pattern verbatim ----
    if (tid < 64) {
        const int l   = tid;
        const int tl  = l >> 5, px = l & 31;
        const int h   = (px >> 2) & 1;
        const int reg = (px & 3) | ((px >> 3) << 2);
        const int bse = h * 32;

        const int ppx = blockIdx.x * 64 + l;       // tl*32+px == l
        const int phw = ppx & (HW - 1);
        const int pb  = ppx >> 13;

        float d[K];
        #pragma unroll
        for (int k = 0; k < K; ++k) {
            const float s = dbuf[tl][0][reg][bse + k] + dbuf[tl][1][reg][bse + k];
            d[k] = sc2f[k] - 2.0f * s;
        }
        int best = 0; float m1 = d[0];
        #pragma unroll
        for (int k = 1; k < K; ++k) if (d[k] < m1) { m1 = d[k]; best = k; }

        unsigned cmask = 0u;
        #pragma unroll
        for (int k = 0; k < K; ++k) if (d[k] - m1 < TAU) cmask |= (1u << k);

        // cooperative exact-f64 resolve of flagged pixels (proven, R8)
        const bool need = (cmask & (cmask - 1)) != 0u;
        unsigned long long ball = __ballot(need);
        while (ball) {
            const int sx = (int)__builtin_ctzll(ball);   // lowest flagged lane
            ball &= ball - 1;
            const unsigned pm  = __shfl(cmask, sx, 64);
            const int      fhw = __shfl(phw,   sx, 64);
            const int      fb  = __shfl(pb,    sx, 64);
            const float* __restrict__ fcol = feat + (size_t)fb * C * HW + fhw;

            const int c0 = tid << 2;                     // channels 4l..4l+3
            double pf[4];
            #pragma unroll
            for (int j = 0; j < 4; ++j)
                pf[j] = (double)fcol[(size_t)(c0 + j) * HW];

            double bd = 1e300; int bi = 0;
            unsigned mm = pm;
            while (mm) {                      // ascending k, strict < tie-break
                const int k = (int)__builtin_ctz(mm);
                mm &= mm - 1;
                const float* __restrict__ ck = cent + (size_t)k * C + c0;
                double s = 0.0;
                #pragma unroll
                for (int j = 0; j < 4; ++j)
                    s = fma(pf[j], (double)ck[j], s);
                #pragma unroll
                for (int off = 1; off < 64; off <<= 1)
                    s += __shfl_xor(s, off, 64);
                const double dk = sc2d[k] - 2.0 * s;
                if (dk < bd) { bd = dk; bi = k; }
            }
            if (tid == sx) best = bi;         // all lanes agree on bi
        }

        // write the 8x8 nearest-upsampled block (R8 verbatim)
        const int w = phw & (WF - 1);
        const int hh = phw >> 7;
        int4 v = make_int4(best, best, best, best);
        int* __restrict__ ob = out + (size_t)map * (BB * HL * WL)
                                   + (size_t)pb * (HL * WL)
                                   + (size_t)(hh * 8) * WL + (size_t)(w * 8);
        #pragma unroll
        for (int r = 0; r < 8; ++r) {
            *(int4*)(ob + (size_t)r * WL)     = v;
            *(int4*)(ob + (size_t)r * WL + 4) = v;
        }
    }
}

extern "C" void kernel_launch(void* const* d_in, const int* in_sizes, int n_in,
                              void* d_out, int out_size, void* d_ws, size_t ws_size,
                              hipStream_t stream) {
    const float* feature_s2t     = (const float*)d_in[0];
    const float* feature_target  = (const float*)d_in[1];
    // d_in[2], d_in[3]: labels — only shapes matter, unused
    const float* centroid_s2t    = (const float*)d_in[4];
    const float* centroid_target = (const float*)d_in[5];
    int* out = (int*)d_out;

    dim3 grid(32768 / 64, 2);   // (512, 2) -> 1024 blocks, 4/CU
    dim3 block(256);
    hipLaunchKernelGGL(centroid_mask_kernel, grid, block, 0, stream,
                       feature_s2t, feature_target,
                       centroid_target, centroid_s2t, out);
}